// Round 12
// baseline (776.949 us; speedup 1.0000x reference)
//
#include <hip/hip_runtime.h>
#include <hip/hip_bf16.h>

typedef __attribute__((ext_vector_type(8))) short short8_t;
typedef __attribute__((ext_vector_type(8))) __bf16 bf16x8;
typedef __attribute__((ext_vector_type(4))) float f32x4;

__device__ __forceinline__ void gload16(const void* g, void* l) {
  __builtin_amdgcn_global_load_lds(
      (const __attribute__((address_space(1))) void*)g,
      (__attribute__((address_space(3))) void*)l, 16, 0, 0);
}

__device__ __forceinline__ unsigned short f2bf(float f) {
  __hip_bfloat16 h = __float2bfloat16(f);
  return __builtin_bit_cast(unsigned short, h);
}

#define BARRIER() asm volatile("s_barrier" ::: "memory")

// ---------------- conversion kernels ----------------

__global__ void k_cvt_feat(const float* __restrict__ in, unsigned short* __restrict__ out) {
  const size_t N = (size_t)4096 * 8192;
  size_t i = ((size_t)blockIdx.x * 256 + threadIdx.x) * 4;
  const size_t stride = (size_t)gridDim.x * 256 * 4;
  for (; i < N; i += stride) {
    float4 v = *(const float4*)(in + i);
    ushort4 o;
    o.x = f2bf(v.x); o.y = f2bf(v.y); o.z = f2bf(v.z); o.w = f2bf(v.w);
    *(ushort4*)(out + i) = o;
  }
}

// W1 f32 [p][8192][256] -> bf16 transposed chunk-local [z][256][8192]
__global__ void k_cvt_w1(const float* __restrict__ W1, unsigned short* __restrict__ out, int p0) {
  __shared__ unsigned short t[64][262];
  const int p = p0 + blockIdx.z;
  const float* src = W1 + (size_t)p * 8192 * 256;
  unsigned short* dst = out + (size_t)blockIdx.z * 256 * 8192;
  const int f0 = blockIdx.x * 256, h0 = blockIdx.y * 64;
#pragma unroll
  for (int i = 0; i < 64; ++i) {
    int tt = i * 256 + threadIdx.x;
    int f = tt >> 6, c = tt & 63;
    t[c][f] = f2bf(src[(size_t)(f0 + f) * 256 + h0 + c]);
  }
  __syncthreads();
#pragma unroll
  for (int i = 0; i < 8; ++i) {
    int tt = i * 256 + threadIdx.x;
    int r = tt >> 5;
    int c8 = (tt & 31) * 8;
    short8_t o;
#pragma unroll
    for (int j = 0; j < 8; ++j) o[j] = (short)t[r][c8 + j];
    *(short8_t*)&dst[(size_t)(h0 + r) * 8192 + f0 + c8] = o;
  }
}

// W2 f32 [p][256][128] -> bf16 transposed [p][128][256]
__global__ void k_cvt_w2(const float* __restrict__ W2, unsigned short* __restrict__ out) {
  const int p = blockIdx.x;
  const float* src = W2 + (size_t)p * 256 * 128;
  unsigned short* dst = out + (size_t)p * 128 * 256;
  for (int tt = threadIdx.x; tt < 128 * 256; tt += 256) {
    int j = tt >> 8, h = tt & 255;
    dst[tt] = f2bf(src[(size_t)h * 128 + j]);
  }
}

// -------- FUSED: out = sigmoid(relu(relu(feat@W1+b1)@W2+b2)@W3+b3) --------
// PIPE-SEPARATED main loop: A (features) loaded global->VGPR directly
// (L3-resident, frag layout = natural 16B loads, double-buffered one tile
// ahead); only B flows through LDS (3x32KB ring, global_load_lds, swizzled).
// LDS pipe drops to 128KB reads + 32KB writes /tile (< 2483cy MFMA); VMEM
// pipe carries A (64KB L2/L3) + B stage (32KB). ONE barrier + ONE counted
// vmcnt(4) per K-tile:
//   [BAR] stage B(t+2) | rdB nj0-3 | vmcnt(4) | 32 MFMA | rdB nj4-7 |
//   loadA(t+1) | 32 MFMA | [BAR]
// FIFO: carry-in {stageB(t+1):4, A(t):8}; +stageB(t+2):4 = 16; vmcnt(4)
// retires stageB(t+1) (ds-read guard for t+1) AND A(t) (issued one full
// tile body ~2500cy earlier >= latency); leaves stageB(t+2).
// Wave layout 4Mx2N (64 rows x 128 cols, acc[4][8]) minimizes A duplication
// (x2) since A now costs VMEM bandwidth.
__global__ __launch_bounds__(512, 2) void k_gemm1(
    const unsigned short* __restrict__ A,    // [4096][8192] bf16
    const unsigned short* __restrict__ Bt,   // [z][256][8192] bf16
    const float* __restrict__ b1,            // [29][256]
    const unsigned short* __restrict__ W2t,  // [29][128][256] bf16
    const float* __restrict__ b2,            // [29][128]
    const float* __restrict__ W3,            // [29][128]
    const float* __restrict__ b3,            // [29]
    float* __restrict__ out,                 // [4096][29]
    int p0) {
  __shared__ __align__(16) unsigned short S[65536];  // loop: first 96KB (3x16384 shorts); epilogue: all 128KB

  const int tid = threadIdx.x;
  const int lane = tid & 63;
  const int wave = tid >> 6;
  const int wm = wave >> 1;   // 0..3: rows wm*64
  const int wn = wave & 1;    // 0..1: cols wn*128

  // bijective chunked XCD swizzle; z-major: 16 consecutive wgs per XCD share
  // predicate z -> B panel L2-resident.
  const int nwg = gridDim.x * gridDim.y;
  const int orig = blockIdx.y * gridDim.x + blockIdx.x;
  const int q = nwg >> 3, r_ = nwg & 7;
  const int xcd = orig & 7, idx = orig >> 3;
  const int wg = (xcd < r_ ? xcd * (q + 1) : r_ * (q + 1) + (xcd - r_) * q) + idx;
  const int mx = wg & 15;     // gridDim.x == 16
  const int z = wg >> 4;
  const int p = p0 + z;
  const int m0 = mx * 256;

  const unsigned short* Ab = A + (size_t)m0 * 8192;
  const unsigned short* Bb = Bt + (size_t)z * 256 * 8192;

  const int l15 = lane & 15, ks = lane >> 4;

  // A lane base: row = wm*64 + mi*16 + l15, k = ks*8 (+ x*32 + t*64)
  const unsigned short* aLane = Ab + (size_t)(wm * 64 + l15) * 8192 + ks * 8;

  // B staging: tile [256 rows][8 units of 16B]; unit e = wave*256 + i*64 + lane;
  // r=e>>3, phys=e&7, global unit=(e&7)^(r&7)  (pre-swizzled source, rule 21)
  unsigned sOff[4];
  int ldOff[4];
#pragma unroll
  for (int i = 0; i < 4; ++i) {
    int e = wave * 256 + i * 64 + lane;
    int r = e >> 3, u = (e & 7) ^ (r & 7);
    sOff[i] = r * 8192 + u * 8;
    ldOff[i] = e * 8;            // shorts; uniform base + lane*16B
  }
  auto stageB = [&](int buf, int T) {
    unsigned short* lb = S + buf * 16384;
    const unsigned short* gb = Bb + (size_t)T * 64;
#pragma unroll
    for (int i = 0; i < 4; ++i) gload16(gb + sOff[i], lb + ldOff[i]);
  };

  auto rdB = [&](int buf, int nj, int x) {
    int R = wn * 128 + nj * 16 + l15;
    int pu = (x * 4 + ks) ^ (R & 7);
    return __builtin_bit_cast(bf16x8, *(const short8_t*)(S + buf * 16384 + R * 64 + pu * 8));
  };

  auto loadA = [&](bf16x8 (&a)[4][2], int T) {
#pragma unroll
    for (int mi = 0; mi < 4; ++mi)
#pragma unroll
      for (int x = 0; x < 2; ++x)
        a[mi][x] = __builtin_bit_cast(bf16x8,
            *(const short8_t*)(aLane + (size_t)mi * 131072 + (size_t)T * 64 + x * 32));
  };

  f32x4 acc[4][8] = {};
  bf16x8 aA[4][2], aB[4][2];
  const int NT = 128;

  auto kstep = [&](int t, bf16x8 (&aC)[4][2], bf16x8 (&aN)[4][2]) {
    const int cur = t % 3;
    if (t + 2 < NT) stageB((t + 2) % 3, t + 2);
    bf16x8 b[4][2];
#pragma unroll
    for (int nj = 0; nj < 4; ++nj) { b[nj][0] = rdB(cur, nj, 0); b[nj][1] = rdB(cur, nj, 1); }
    if (t + 2 < NT) asm volatile("s_waitcnt vmcnt(4)" ::: "memory");
    else            asm volatile("s_waitcnt vmcnt(0)" ::: "memory");
    __builtin_amdgcn_s_setprio(1);
#pragma unroll
    for (int mi = 0; mi < 4; ++mi)
#pragma unroll
      for (int nj = 0; nj < 4; ++nj) {
        acc[mi][nj] = __builtin_amdgcn_mfma_f32_16x16x32_bf16(aC[mi][0], b[nj][0], acc[mi][nj], 0, 0, 0);
        acc[mi][nj] = __builtin_amdgcn_mfma_f32_16x16x32_bf16(aC[mi][1], b[nj][1], acc[mi][nj], 0, 0, 0);
      }
    __builtin_amdgcn_s_setprio(0);
#pragma unroll
    for (int nj = 0; nj < 4; ++nj) { b[nj][0] = rdB(cur, nj + 4, 0); b[nj][1] = rdB(cur, nj + 4, 1); }
    if (t + 1 < NT) loadA(aN, t + 1);
    __builtin_amdgcn_s_setprio(1);
#pragma unroll
    for (int mi = 0; mi < 4; ++mi)
#pragma unroll
      for (int nj = 0; nj < 4; ++nj) {
        acc[mi][nj + 4] = __builtin_amdgcn_mfma_f32_16x16x32_bf16(aC[mi][0], b[nj][0], acc[mi][nj + 4], 0, 0, 0);
        acc[mi][nj + 4] = __builtin_amdgcn_mfma_f32_16x16x32_bf16(aC[mi][1], b[nj][1], acc[mi][nj + 4], 0, 0, 0);
      }
    __builtin_amdgcn_s_setprio(0);
    BARRIER();
  };

  // prologue: stage B(0),B(1); A(0) to regs; vmcnt(12) retires stage B(0).
  stageB(0, 0); stageB(1, 1);
  loadA(aA, 0);
  asm volatile("s_waitcnt vmcnt(12)" ::: "memory");
  BARRIER();

  for (int t = 0; t < NT; t += 2) {
    kstep(t, aA, aB);
    kstep(t + 1, aB, aA);
  }

  // ---- fused epilogue ----
  // 1) h1 = relu(acc + b1) -> LDS [256 rows][32 units of 16B], unit u of
  //    row R at phys u^(R&7).
  __syncthreads();
  {
#pragma unroll
    for (int nj = 0; nj < 8; ++nj) {
      const int c = wn * 128 + nj * 16 + l15;
      const float bb = b1[p * 256 + c];
      const int u = c >> 3, sub = c & 7;
#pragma unroll
      for (int mi = 0; mi < 4; ++mi) {
        const int Rb = wm * 64 + mi * 16 + ks * 4;
#pragma unroll
        for (int rr = 0; rr < 4; ++rr) {
          const int R = Rb + rr;
          float v = acc[mi][nj][rr] + bb;
          v = v > 0.f ? v : 0.f;
          S[R * 256 + ((u ^ (R & 7)) * 8) + sub] = f2bf(v);
        }
      }
    }
  }
  __syncthreads();
  // 2) GEMM2: wave owns rows wave*32..+32, cols 0..127, K=256; A from LDS,
  //    B=W2t frags from global (L2-resident).
  {
    const unsigned short* Wp = W2t + (size_t)p * 128 * 256;
    f32x4 acc2[2][8] = {};
    bf16x8 bcur[8], bnxt[8];
#pragma unroll
    for (int nj = 0; nj < 8; ++nj)
      bcur[nj] = __builtin_bit_cast(bf16x8, *(const short8_t*)(Wp + (nj * 16 + l15) * 256 + ks * 8));
#pragma unroll
    for (int kt = 0; kt < 8; ++kt) {
      if (kt < 7) {
#pragma unroll
        for (int nj = 0; nj < 8; ++nj)
          bnxt[nj] = __builtin_bit_cast(bf16x8, *(const short8_t*)(Wp + (nj * 16 + l15) * 256 + (kt + 1) * 32 + ks * 8));
      }
      bf16x8 a2[2];
#pragma unroll
      for (int mi = 0; mi < 2; ++mi) {
        const int R = wave * 32 + mi * 16 + l15;
        const int u = kt * 4 + ks;
        a2[mi] = __builtin_bit_cast(bf16x8, *(const short8_t*)(S + R * 256 + ((u ^ (R & 7)) * 8)));
      }
#pragma unroll
      for (int mi = 0; mi < 2; ++mi)
#pragma unroll
        for (int nj = 0; nj < 8; ++nj)
          acc2[mi][nj] = __builtin_amdgcn_mfma_f32_16x16x32_bf16(a2[mi], bcur[nj], acc2[mi][nj], 0, 0, 0);
#pragma unroll
      for (int nj = 0; nj < 8; ++nj) bcur[nj] = bnxt[nj];
    }
    float b2v[8], w3v[8];
#pragma unroll
    for (int nj = 0; nj < 8; ++nj) {
      int c = nj * 16 + l15;
      b2v[nj] = b2[p * 128 + c];
      w3v[nj] = W3[p * 128 + c];
    }
    const float b3p = b3[p];
#pragma unroll
    for (int mi = 0; mi < 2; ++mi) {
#pragma unroll
      for (int r = 0; r < 4; ++r) {
        float s = 0.f;
#pragma unroll
        for (int nj = 0; nj < 8; ++nj) {
          float v = acc2[mi][nj][r] + b2v[nj];
          v = v > 0.f ? v : 0.f;
          s += v * w3v[nj];
        }
        s += __shfl_xor(s, 1);
        s += __shfl_xor(s, 2);
        s += __shfl_xor(s, 4);
        s += __shfl_xor(s, 8);
        if (l15 == 0) {
          int m = m0 + wave * 32 + mi * 16 + ks * 4 + r;
          float logit = s + b3p;
          out[(size_t)m * 29 + p] = 1.f / (1.f + __expf(-logit));
        }
      }
    }
  }
}

// ---------------- launch ----------------
extern "C" void kernel_launch(void* const* d_in, const int* in_sizes, int n_in,
                              void* d_out, int out_size, void* d_ws, size_t ws_size,
                              hipStream_t stream) {
  const float* features = (const float*)d_in[0];
  const float* W1 = (const float*)d_in[1];
  const float* b1 = (const float*)d_in[2];
  const float* W2 = (const float*)d_in[3];
  const float* b2 = (const float*)d_in[4];
  const float* W3 = (const float*)d_in[5];
  const float* b3 = (const float*)d_in[6];
  float* out = (float*)d_out;

  char* ws = (char*)d_ws;
  const size_t featB = (size_t)4096 * 8192 * 2;       // 64 MB
  const size_t w2B   = (size_t)29 * 128 * 256 * 2;    // 1.9 MB
  const size_t w1pp  = (size_t)256 * 8192 * 2;        // 4 MB per predicate

  unsigned short* featbf = (unsigned short*)ws;
  unsigned short* w2t    = (unsigned short*)(ws + featB);
  unsigned short* w1t    = (unsigned short*)(ws + featB + w2B);

  size_t base = featB + w2B;
  size_t rem = (ws_size > base) ? (ws_size - base) : 0;
  int CH = (int)(rem / w1pp);
  if (CH > 29) CH = 29;
  if (CH < 1) CH = 1;

  k_cvt_feat<<<2048, 256, 0, stream>>>(features, featbf);
  k_cvt_w2<<<29, 256, 0, stream>>>(W2, w2t);

  for (int p0 = 0; p0 < 29; p0 += CH) {
    int c = (29 - p0) < CH ? (29 - p0) : CH;
    k_cvt_w1<<<dim3(32, 4, c), 256, 0, stream>>>(W1, w1t, p0);
    k_gemm1<<<dim3(16, c), 512, 0, stream>>>(featbf, w1t, b1, w2t, b2, W3, b3, out, p0);
  }
}